// Round 2
// baseline (298.890 us; speedup 1.0000x reference)
//
#include <hip/hip_runtime.h>

#define RAYS 65536
#define NS   192

__device__ __forceinline__ void cswap(float &a, float &b, bool up){
    float mn = fminf(a, b), mx = fmaxf(a, b);
    a = up ? mn : mx;
    b = up ? mx : mn;
}

// cross-lane bitonic phase: lane-distance JL (= j/4), 4 elements per lane
template<int JL>
__device__ __forceinline__ void xphase(float v[4], bool up, int lane){
    bool takeMin = (up == ((lane & JL) == 0));
    #pragma unroll
    for (int r = 0; r < 4; ++r){
        float p  = __shfl_xor(v[r], JL, 64);
        float mn = fminf(v[r], p), mx = fmaxf(v[r], p);
        v[r] = takeMin ? mn : mx;
    }
}

__global__ __launch_bounds__(256) void nerf_integrate(
    const float* __restrict__ t,
    const float* __restrict__ sigma,
    const float* __restrict__ c,
    float* __restrict__ out)
{
    const int wave = threadIdx.x >> 6;
    const int lane = threadIdx.x & 63;
    const int ray  = blockIdx.x * 4 + wave;

    // ---- load t (193 fp32 vals) into e = 4*lane + r, pad with big ----
    const float* trow = t + (size_t)ray * 193;
    float v[4];
    #pragma unroll
    for (int r = 0; r < 4; ++r){
        int e = 4 * lane + r;
        v[r] = (e <= 192) ? trow[e] : 1e30f;
    }

    // ---- bitonic sort of 256 (ascending), index bits: [1:0]=r, [7:2]=lane ----
    bool up;
    // k=2
    cswap(v[0], v[1], true);  cswap(v[2], v[3], false);
    // k=4
    up = ((lane & 1) == 0);
    cswap(v[0], v[2], up); cswap(v[1], v[3], up);
    cswap(v[0], v[1], up); cswap(v[2], v[3], up);
    // k=8
    up = ((lane & 2) == 0);
    xphase<1>(v, up, lane);
    cswap(v[0], v[2], up); cswap(v[1], v[3], up);
    cswap(v[0], v[1], up); cswap(v[2], v[3], up);
    // k=16
    up = ((lane & 4) == 0);
    xphase<2>(v, up, lane); xphase<1>(v, up, lane);
    cswap(v[0], v[2], up); cswap(v[1], v[3], up);
    cswap(v[0], v[1], up); cswap(v[2], v[3], up);
    // k=32
    up = ((lane & 8) == 0);
    xphase<4>(v, up, lane); xphase<2>(v, up, lane); xphase<1>(v, up, lane);
    cswap(v[0], v[2], up); cswap(v[1], v[3], up);
    cswap(v[0], v[1], up); cswap(v[2], v[3], up);
    // k=64
    up = ((lane & 16) == 0);
    xphase<8>(v, up, lane); xphase<4>(v, up, lane); xphase<2>(v, up, lane); xphase<1>(v, up, lane);
    cswap(v[0], v[2], up); cswap(v[1], v[3], up);
    cswap(v[0], v[1], up); cswap(v[2], v[3], up);
    // k=128
    up = ((lane & 32) == 0);
    xphase<16>(v, up, lane); xphase<8>(v, up, lane); xphase<4>(v, up, lane);
    xphase<2>(v, up, lane);  xphase<1>(v, up, lane);
    cswap(v[0], v[2], up); cswap(v[1], v[3], up);
    cswap(v[0], v[1], up); cswap(v[2], v[3], up);
    // k=256 (final merge, all ascending)
    xphase<32>(v, true, lane); xphase<16>(v, true, lane); xphase<8>(v, true, lane);
    xphase<4>(v, true, lane);  xphase<2>(v, true, lane);  xphase<1>(v, true, lane);
    cswap(v[0], v[2], true); cswap(v[1], v[3], true);
    cswap(v[0], v[1], true); cswap(v[2], v[3], true);

    // ---- dt / sdt (cross-lane op BEFORE divergence) ----
    float nxt0 = __shfl_down(v[0], 1, 64);   // sorted[e+1] for r=3
    const bool active = (lane < 48);         // e < 192

    float sg[4] = {0.f, 0.f, 0.f, 0.f};
    float cv[12];
    if (active){
        const float4 s4 = *reinterpret_cast<const float4*>(sigma + (size_t)ray * NS + 4 * lane);
        sg[0] = s4.x; sg[1] = s4.y; sg[2] = s4.z; sg[3] = s4.w;
        const float* crow = c + (size_t)ray * (NS * 3) + 12 * lane;
        const float4 c0 = *reinterpret_cast<const float4*>(crow);
        const float4 c1 = *reinterpret_cast<const float4*>(crow + 4);
        const float4 c2 = *reinterpret_cast<const float4*>(crow + 8);
        cv[0]=c0.x; cv[1]=c0.y; cv[2] =c0.z; cv[3] =c0.w;
        cv[4]=c1.x; cv[5]=c1.y; cv[6] =c1.z; cv[7] =c1.w;
        cv[8]=c2.x; cv[9]=c2.y; cv[10]=c2.z; cv[11]=c2.w;
    }

    float sdt[4];
    #pragma unroll
    for (int r = 0; r < 4; ++r){
        float tn = (r < 3) ? v[r + 1] : nxt0;
        float d  = tn - v[r];
        sdt[r] = active ? sg[r] * d : 0.0f;
    }

    // ---- exclusive prefix sum of sdt across the wave ----
    float s1   = sdt[0] + sdt[1];
    float inc2 = s1 + sdt[2];
    float tot  = inc2 + sdt[3];
    float x = tot;                     // inclusive scan of lane totals
    #pragma unroll
    for (int d = 1; d < 64; d <<= 1){
        float y = __shfl_up(x, d, 64);
        if (lane >= d) x += y;
    }
    float laneExcl = x - tot;
    float ex[4];
    ex[0] = laneExcl;
    ex[1] = laneExcl + sdt[0];
    ex[2] = laneExcl + s1;
    ex[3] = laneExcl + inc2;

    // ---- wi = exp(-excl) - exp(-incl);  rgb accumulate ----
    float wi[4];
    #pragma unroll
    for (int r = 0; r < 4; ++r){
        float T0 = __expf(-ex[r]);
        float T1 = __expf(-(ex[r] + sdt[r]));
        wi[r] = T0 - T1;
    }

    float a0 = 0.f, a1 = 0.f, a2 = 0.f;
    if (active){
        #pragma unroll
        for (int r = 0; r < 4; ++r){
            a0 += wi[r] * cv[3 * r + 0];
            a1 += wi[r] * cv[3 * r + 1];
            a2 += wi[r] * cv[3 * r + 2];
        }
        float4 w4;
        w4.x = wi[0]; w4.y = wi[1]; w4.z = wi[2]; w4.w = wi[3];
        *reinterpret_cast<float4*>(out + (size_t)RAYS * 3 + (size_t)ray * NS + 4 * lane) = w4;
    }

    // ---- wave reduction for rgb (inactive lanes contribute 0) ----
    #pragma unroll
    for (int d = 32; d >= 1; d >>= 1){
        a0 += __shfl_xor(a0, d, 64);
        a1 += __shfl_xor(a1, d, 64);
        a2 += __shfl_xor(a2, d, 64);
    }
    if (lane < 3){
        float val = (lane == 0) ? a0 : ((lane == 1) ? a1 : a2);
        out[(size_t)ray * 3 + lane] = val;
    }
}

extern "C" void kernel_launch(void* const* d_in, const int* in_sizes, int n_in,
                              void* d_out, int out_size, void* d_ws, size_t ws_size,
                              hipStream_t stream) {
    const float* t     = (const float*)d_in[0];
    const float* sigma = (const float*)d_in[1];
    const float* c     = (const float*)d_in[2];
    float* out = (float*)d_out;
    nerf_integrate<<<RAYS / 4, 256, 0, stream>>>(t, sigma, c, out);
}

// Round 3
// 293.090 us; speedup vs baseline: 1.0198x; 1.0198x over previous
//
#include <hip/hip_runtime.h>

#define RAYS 65536
#define NS   192

__device__ __forceinline__ int   f2i(float x){ return __builtin_bit_cast(int, x); }
__device__ __forceinline__ float i2f(int x)  { return __builtin_bit_cast(float, x); }

// v_mov_b32_dpp with old=0, bound_ctrl:0 (invalid lanes -> 0), bank_mask 0xF
template<int CTRL, int ROWMASK>
__device__ __forceinline__ float dpp0(float x){
    return i2f(__builtin_amdgcn_update_dpp(0, f2i(x), CTRL, ROWMASK, 0xF, true));
}
template<int OFF>
__device__ __forceinline__ float swz(float x){
    return i2f(__builtin_amdgcn_ds_swizzle(f2i(x), OFF));
}

// partner value at sub-lane distance JL (within each 32-lane half)
template<int JL>
__device__ __forceinline__ float partner(float x){
    if      constexpr (JL == 1) return dpp0<0xB1, 0xF>(x);   // quad_perm [1,0,3,2] = xor1
    else if constexpr (JL == 2) return dpp0<0x4E, 0xF>(x);   // quad_perm [2,3,0,1] = xor2
    else if constexpr (JL == 4) return swz<0x101F>(x);       // xor4
    else if constexpr (JL == 8) return swz<0x201F>(x);       // xor8
    else                        return swz<0x401F>(x);       // xor16
}

__device__ __forceinline__ void cswap(float &a, float &b, bool up){
    float mn = fminf(a, b), mx = fmaxf(a, b);
    a = up ? mn : mx;
    b = up ? mx : mn;
}

// in-register phase j = J (J in {1,2,4}), uniform direction
template<int J>
__device__ __forceinline__ void rphase(float v[8], bool up){
    #pragma unroll
    for (int r = 0; r < 8; ++r)
        if ((r & J) == 0) cswap(v[r], v[r ^ J], up);
}

// cross-lane phase, lane distance JL
template<int JL>
__device__ __forceinline__ void xphase(float v[8], bool takeMin){
    #pragma unroll
    for (int r = 0; r < 8; ++r){
        float p  = partner<JL>(v[r]);
        float mn = fminf(v[r], p), mx = fmaxf(v[r], p);
        v[r] = takeMin ? mn : mx;
    }
}

// 32-lane butterfly sum (both halves independently)
__device__ __forceinline__ float halfsum(float a){
    a += dpp0<0xB1, 0xF>(a);
    a += dpp0<0x4E, 0xF>(a);
    a += swz<0x101F>(a);
    a += swz<0x201F>(a);
    a += swz<0x401F>(a);
    return a;
}

__global__ __launch_bounds__(256) void nerf_integrate(
    const float* __restrict__ t,
    const float* __restrict__ sigma,
    const float* __restrict__ c,
    float* __restrict__ out)
{
    const int tid  = threadIdx.x;
    const int lane = tid & 63;
    const int sl   = tid & 31;                     // sub-lane within the ray's 32 lanes
    const int ray  = blockIdx.x * 8 + (tid >> 5);  // 2 rays per wave, 8 per block

    // ---- load t: element e = 8*sl + r (193 real values, pad 1e30) ----
    const float* trow = t + (size_t)ray * 193;
    float v[8];
    if (sl < 24){
        #pragma unroll
        for (int r = 0; r < 8; ++r) v[r] = trow[8 * sl + r];
    } else if (sl == 24){
        v[0] = trow[192];
        #pragma unroll
        for (int r = 1; r < 8; ++r) v[r] = 1e30f;
    } else {
        #pragma unroll
        for (int r = 0; r < 8; ++r) v[r] = 1e30f;
    }

    // ---- bitonic sort of 256: index bits [2:0]=r, [7:3]=sl ----
    bool up;
    // k=2 (j=1): up = ((r&2)==0)
    cswap(v[0],v[1],true);  cswap(v[2],v[3],false);
    cswap(v[4],v[5],true);  cswap(v[6],v[7],false);
    // k=4: up = ((r&4)==0)
    cswap(v[0],v[2],true);  cswap(v[1],v[3],true);
    cswap(v[4],v[6],false); cswap(v[5],v[7],false);
    cswap(v[0],v[1],true);  cswap(v[2],v[3],true);
    cswap(v[4],v[5],false); cswap(v[6],v[7],false);
    // k=8: up = ((sl&1)==0)
    up = ((sl & 1) == 0);
    rphase<4>(v, up); rphase<2>(v, up); rphase<1>(v, up);
    // k=16: up = ((sl&2)==0); j=8 cross (JL=1), then in-reg
    up = ((sl & 2) == 0);
    xphase<1>(v, up == ((sl & 1) == 0));
    rphase<4>(v, up); rphase<2>(v, up); rphase<1>(v, up);
    // k=32
    up = ((sl & 4) == 0);
    xphase<2>(v, up == ((sl & 2) == 0));
    xphase<1>(v, up == ((sl & 1) == 0));
    rphase<4>(v, up); rphase<2>(v, up); rphase<1>(v, up);
    // k=64
    up = ((sl & 8) == 0);
    xphase<4>(v, up == ((sl & 4) == 0));
    xphase<2>(v, up == ((sl & 2) == 0));
    xphase<1>(v, up == ((sl & 1) == 0));
    rphase<4>(v, up); rphase<2>(v, up); rphase<1>(v, up);
    // k=128
    up = ((sl & 16) == 0);
    xphase<8>(v, up == ((sl & 8) == 0));
    xphase<4>(v, up == ((sl & 4) == 0));
    xphase<2>(v, up == ((sl & 2) == 0));
    xphase<1>(v, up == ((sl & 1) == 0));
    rphase<4>(v, up); rphase<2>(v, up); rphase<1>(v, up);
    // k=256 (ascending everywhere)
    xphase<16>(v, ((sl & 16) == 0));
    xphase<8> (v, ((sl & 8)  == 0));
    xphase<4> (v, ((sl & 4)  == 0));
    xphase<2> (v, ((sl & 2)  == 0));
    xphase<1> (v, ((sl & 1)  == 0));
    rphase<4>(v, true); rphase<2>(v, true); rphase<1>(v, true);

    // ---- neighbor for r=7 (cross-lane before any divergence) ----
    float nxt = __shfl(v[0], lane + 1, 64);  // lane31/63 are pads -> don't care
    const bool act = (sl < 24);              // lane's 8 elements all < 192

    // ---- sigma, sdt ----
    float sg[8];
    if (act){
        const float* srow = sigma + (size_t)ray * NS + 8 * sl;
        float4 s0 = *reinterpret_cast<const float4*>(srow);
        float4 s1 = *reinterpret_cast<const float4*>(srow + 4);
        sg[0]=s0.x; sg[1]=s0.y; sg[2]=s0.z; sg[3]=s0.w;
        sg[4]=s1.x; sg[5]=s1.y; sg[6]=s1.z; sg[7]=s1.w;
    } else {
        #pragma unroll
        for (int r = 0; r < 8; ++r) sg[r] = 0.0f;
    }
    float sdt[8];
    #pragma unroll
    for (int r = 0; r < 8; ++r){
        float tn = (r < 7) ? v[r + 1] : nxt;
        sdt[r] = act ? sg[r] * (tn - v[r]) : 0.0f;
    }

    // ---- prefix sum: in-lane inclusive over 8, then per-half DPP scan ----
    float pre[8];
    float run = 0.0f;
    #pragma unroll
    for (int r = 0; r < 8; ++r){ run += sdt[r]; pre[r] = run; }
    float x = run;
    x += dpp0<0x111, 0xF>(x);   // row_shr:1
    x += dpp0<0x112, 0xF>(x);   // row_shr:2
    x += dpp0<0x114, 0xF>(x);   // row_shr:4
    x += dpp0<0x118, 0xF>(x);   // row_shr:8
    x += dpp0<0x142, 0xA>(x);   // row_bcast:15 into rows 1,3 (per-half scan)
    float laneExcl = x - run;

    // ---- wi = exp(-excl) - exp(-incl) ----
    float wi[8];
    #pragma unroll
    for (int r = 0; r < 8; ++r){
        float incl = laneExcl + pre[r];
        float excl = incl - sdt[r];
        wi[r] = __expf(-excl) - __expf(-incl);
    }
    if (act){
        float* wrow = out + (size_t)RAYS * 3 + (size_t)ray * NS + 8 * sl;
        *reinterpret_cast<float4*>(wrow)     = make_float4(wi[0], wi[1], wi[2], wi[3]);
        *reinterpret_cast<float4*>(wrow + 4) = make_float4(wi[4], wi[5], wi[6], wi[7]);
    }

    // ---- rgb: load c, accumulate, per-half reduce ----
    float a0 = 0.f, a1 = 0.f, a2 = 0.f;
    if (act){
        const float* crow = c + (size_t)ray * (NS * 3) + 24 * sl;
        float cf[24];
        #pragma unroll
        for (int m = 0; m < 6; ++m){
            float4 cc = *reinterpret_cast<const float4*>(crow + 4 * m);
            cf[4*m+0]=cc.x; cf[4*m+1]=cc.y; cf[4*m+2]=cc.z; cf[4*m+3]=cc.w;
        }
        #pragma unroll
        for (int r = 0; r < 8; ++r){
            a0 += wi[r] * cf[3*r + 0];
            a1 += wi[r] * cf[3*r + 1];
            a2 += wi[r] * cf[3*r + 2];
        }
    }
    a0 = halfsum(a0);
    a1 = halfsum(a1);
    a2 = halfsum(a2);
    if (sl < 3){
        float val = (sl == 0) ? a0 : ((sl == 1) ? a1 : a2);
        out[(size_t)ray * 3 + sl] = val;
    }
}

extern "C" void kernel_launch(void* const* d_in, const int* in_sizes, int n_in,
                              void* d_out, int out_size, void* d_ws, size_t ws_size,
                              hipStream_t stream) {
    const float* t     = (const float*)d_in[0];
    const float* sigma = (const float*)d_in[1];
    const float* c     = (const float*)d_in[2];
    float* out = (float*)d_out;
    nerf_integrate<<<RAYS / 8, 256, 0, stream>>>(t, sigma, c, out);
}